// Round 5
// baseline (589.882 us; speedup 1.0000x reference)
//
#include <hip/hip_runtime.h>
#include <cstdint>
#include <cstddef>

#define B_   2
#define L_   4096
#define DM_  1024
#define DI_  2048
#define DT_  64
#define M_   (B_*L_)      // 8192 rows
#define G_   64           // scan chunks per row
#define CH_  (L_/G_)      // 64 elements per chunk
#define KSPL 8            // split-K factor for dt_low GEMM
#define KSL  (DI_/KSPL)   // 256 per split
#define BK_  32           // GEMM k-tile: BK=64 measured REGRESSIVE (R4: 132 vs 117 us)

typedef __bf16 bf16;
typedef __bf16 bf16x8 __attribute__((ext_vector_type(8)));
typedef __bf16 bf16x4 __attribute__((ext_vector_type(4)));
typedef float  f32x4  __attribute__((ext_vector_type(4)));

__device__ __forceinline__ float silu_f(float x){ return x / (1.f + __expf(-x)); }

// async global->LDS, 16B per lane. LDS dest = wave-uniform base + lane*16
// (m104/m108) -> LDS layout must be plain row-major unpadded.
__device__ __forceinline__ void gl_lds16(const bf16* g, bf16* l){
  __builtin_amdgcn_global_load_lds(
      (const __attribute__((address_space(1))) void*)g,
      (__attribute__((address_space(3))) void*)l, 16, 0, 0);
}

// ---------------- fused fp32 -> bf16 conversion for all 5 weight/input tensors
__global__ __launch_bounds__(256)
void cvt_all_kernel(const float4* __restrict__ s0, bf16x4* __restrict__ d0, int n0,
                    const float4* __restrict__ s1, bf16x4* __restrict__ d1, int n1,
                    const float4* __restrict__ s2, bf16x4* __restrict__ d2, int n2,
                    const float4* __restrict__ s3, bf16x4* __restrict__ d3, int n3,
                    const float4* __restrict__ s4, bf16x4* __restrict__ d4, int n4)
{
  int i = blockIdx.x*256 + threadIdx.x;
  const float4* s; bf16x4* d;
  if      (i < n0)                 { s = s0; d = d0; }
  else if ((i -= n0) < n1)         { s = s1; d = d1; }
  else if ((i -= n1) < n2)         { s = s2; d = d2; }
  else if ((i -= n2) < n3)         { s = s3; d = d3; }
  else if ((i -= n3) < n4)         { s = s4; d = d4; }
  else return;
  float4 v = s[i];
  bf16x4 o = {(bf16)v.x, (bf16)v.y, (bf16)v.z, (bf16)v.w};
  d[i] = o;
}

// ---------------- GEMM: C[M,N] = A[M,K] * W[N,K]^T, bf16 MFMA ----------------
// m97 structure: 128x128 macro-tile, BK=32, 4 waves 2x2, 4x4 frags each,
// global_load_lds width-16 staging, unpadded LDS (row = 32 bf16 = 64B,
// fragment reads 2-way bank aliasing = free per m136).
// EPI: 0 = in_proj split (xi bf16 + g=silu(z) bf16)
//      2 = dt epilogue   (softplus/clip -> delta bf16)
//      3 = plain fp32 store (final output)
//      4 = split-K partial fp32 (dt_low), K-range from blockIdx.z
template<int EPI>
__global__ __launch_bounds__(256)
void gemm_bt(const bf16* __restrict__ A, const bf16* __restrict__ W,
             int M, int N, int K,
             float* __restrict__ o0, bf16* __restrict__ ob, bf16* __restrict__ ob2,
             const float* __restrict__ bias)
{
  __shared__ bf16 As[128*BK_];
  __shared__ bf16 Bs[128*BK_];
  const int t    = threadIdx.x;
  const int lane = t & 63;
  const int wave = t >> 6;
  const int wm   = wave >> 1, wn = wave & 1;
  const int l16  = lane & 15, quad = lane >> 4;
  const int m0   = blockIdx.y * 128, n0 = blockIdx.x * 128;

  // staging: wave stages rows [wave*32, wave*32+32), 2 issues per operand,
  // each issue = 16 rows x 64B = 64 lanes x 16B
  const int srow = (lane >> 2);        // 0..15 within issue
  const int scol = (lane & 3) * 8;     // element col: 0,8,16,24

  f32x4 acc[4][4] = {};

  const int kbase   = (EPI == 4) ? (int)blockIdx.z * KSL : 0;
  const int kframes = (EPI == 4) ? (KSL / BK_) : (K / BK_);

  for (int kt = 0; kt < kframes; ++kt){
    const int k0 = kbase + kt * BK_;
    #pragma unroll
    for (int j = 0; j < 2; ++j){
      const int row16 = wave*32 + j*16;
      int rA = m0 + row16 + srow; if (rA >= M) rA = M - 1;
      int rB = n0 + row16 + srow; if (rB >= N) rB = N - 1;   // clamp for N<128
      gl_lds16(A + (size_t)rA*K + k0 + scol, &As[row16*BK_]);
      gl_lds16(W + (size_t)rB*K + k0 + scol, &Bs[row16*BK_]);
    }
    __syncthreads();
    bf16x8 af[4], bf_[4];
    #pragma unroll
    for (int i = 0; i < 4; ++i){
      af[i]  = *(const bf16x8*)&As[(wm*64 + i*16 + l16)*BK_ + quad*8];
      bf_[i] = *(const bf16x8*)&Bs[(wn*64 + i*16 + l16)*BK_ + quad*8];
    }
    #pragma unroll
    for (int mi = 0; mi < 4; ++mi)
      #pragma unroll
      for (int ni = 0; ni < 4; ++ni)
        acc[mi][ni] = __builtin_amdgcn_mfma_f32_16x16x32_bf16(af[mi], bf_[ni], acc[mi][ni], 0, 0, 0);
    __syncthreads();
  }

  // C/D layout (m89/m91 verified): col = lane&15, row = (lane>>4)*4 + reg
  #pragma unroll
  for (int mi = 0; mi < 4; ++mi){
    #pragma unroll
    for (int ni = 0; ni < 4; ++ni){
      const int n = n0 + wn*64 + ni*16 + l16;
      if (n < N){
        #pragma unroll
        for (int r = 0; r < 4; ++r){
          const int m = m0 + wm*64 + mi*16 + quad*4 + r;
          float v = acc[mi][ni][r];
          if (EPI == 0){
            // in_proj split: n<DI -> xi (bf16), n>=DI -> g = silu(z) (bf16)
            if (n < DI_) ob [(size_t)m*DI_ + n]         = (bf16)v;
            else         ob2[(size_t)m*DI_ + (n - DI_)] = (bf16)silu_f(v);
          } else if (EPI == 2){
            // delta = clip(softplus(v+b),1e-6,10)  -> bf16 (e computed in scan)
            float vv = v + bias[n];
            float delta = (vv > 20.f) ? vv : log1pf(__expf(vv));
            delta = fminf(fmaxf(delta, 1e-6f), 10.f);
            ob[(size_t)m*N + n] = (bf16)delta;
          } else if (EPI == 4){
            o0[((size_t)blockIdx.z*M_ + m)*DT_ + n] = v;   // split-K partial
          } else {
            o0[(size_t)m*N + n] = v;                       // final fp32
          }
        }
      }
    }
  }
}

// ---------------- split-K reduce: dtl = sum_z partial[z] (bf16) ----------------
__global__ __launch_bounds__(256)
void dt_reduce_kernel(const float* __restrict__ part, bf16* __restrict__ dtl){
  const int i = blockIdx.x*256 + threadIdx.x;   // m*DT + n
  float s = 0.f;
  #pragma unroll
  for (int z = 0; z < KSPL; ++z) s += part[(size_t)z*M_*DT_ + i];
  dtl[i] = (bf16)s;
}

// ---------------- depthwise causal conv (K=4) + bias + SiLU ----------------
__global__ __launch_bounds__(256)
void conv_silu_kernel(const bf16* __restrict__ xi, const float* __restrict__ cw,
                      const float* __restrict__ cb, bf16* __restrict__ ubf)
{
  const int idx = blockIdx.x*256 + threadIdx.x;    // (b,l,d) flat, coalesced in d
  const int d = idx & (DI_-1);
  const int l = (idx >> 11) & (L_-1);              // DI_=2^11, L_=2^12
  float s = cb[d];
  #pragma unroll
  for (int k = 0; k < 4; ++k){
    const int ll = l + k - 3;
    if (ll >= 0) s += (float)xi[idx + (k-3)*DI_] * cw[d*4 + k];
  }
  ubf[idx] = (bf16)silu_f(s);
}

// ---------------- selective scan: 3-pass chunked linear scan ----------------
// e = clip(exp(delta*A),1e-6,1) computed on the fly from bf16 delta (log-domain
// error |A|*delta*0.4% ~ 6e-4, better than bf16-rounding e itself).
// s_l = e_l*s_{l-1} + u_l; |u|<~1 so |s| stays O(10), the +-1e4 clip is
// provably inactive -> linear chunk decomposition is exact.
__device__ __forceinline__ float e_of(float delta, float Ad){
  float ee = __expf(delta * Ad);
  return fminf(fmaxf(ee, 1e-6f), 1.f);
}
__device__ __forceinline__ float a_of(const float* alog, int d){
  float Ad = -__expf(alog[d]);
  return fminf(fmaxf(Ad, -10.f), -1e-6f);
}

__global__ __launch_bounds__(256)
void scan_pass1(const bf16* __restrict__ delta, const bf16* __restrict__ u,
                const float* __restrict__ alog,
                float* __restrict__ P, float* __restrict__ F)
{
  const int d = blockIdx.x*256 + threadIdx.x;
  const int c = blockIdx.y, b = blockIdx.z;
  const float Ad = a_of(alog, d);
  size_t base = ((size_t)(b*L_ + c*CH_))*DI_ + d;
  float p = 1.f, f = 0.f;
  for (int i = 0; i < CH_; ++i){
    float ee = e_of((float)delta[base + (size_t)i*DI_], Ad);
    float uu = (float)u[base + (size_t)i*DI_];
    f = f*ee + uu;
    p *= ee;
  }
  const size_t o = ((size_t)b*G_ + c)*DI_ + d;
  P[o] = p; F[o] = f;
}

__global__ __launch_bounds__(256)
void scan_pass2(const float* __restrict__ P, const float* __restrict__ F,
                float* __restrict__ Sin)
{
  const int idx = blockIdx.x*256 + threadIdx.x;    // b*DI + d
  const int d = idx & (DI_-1);
  const int b = idx >> 11;
  float s = 0.f;
  for (int c = 0; c < G_; ++c){
    const size_t o = ((size_t)b*G_ + c)*DI_ + d;
    Sin[o] = s;
    s = F[o] + P[o]*s;
  }
}

__global__ __launch_bounds__(256)
void scan_pass3(const bf16* __restrict__ delta, const bf16* __restrict__ u,
                const bf16* __restrict__ g, const float* __restrict__ Sin,
                const float* __restrict__ alog, const float* __restrict__ Dp,
                bf16* __restrict__ y)
{
  const int d = blockIdx.x*256 + threadIdx.x;
  const int c = blockIdx.y, b = blockIdx.z;
  const float Ad = a_of(alog, d);
  size_t base = ((size_t)(b*L_ + c*CH_))*DI_ + d;
  float s = Sin[((size_t)b*G_ + c)*DI_ + d];
  const float Dd = Dp[d];
  for (int i = 0; i < CH_; ++i){
    const size_t idx = base + (size_t)i*DI_;
    const float uu = (float)u[idx];
    s = s*e_of((float)delta[idx], Ad) + uu;
    float yy = s + uu*Dd;
    yy = fminf(fmaxf(yy, -1e4f), 1e4f);
    yy *= (float)g[idx];              // g = silu(z), from GEMM1 epilogue
    y[idx] = (bf16)yy;
  }
}

// ---------------- host launch ----------------
extern "C" void kernel_launch(void* const* d_in, const int* in_sizes, int n_in,
                              void* d_out, int out_size, void* d_ws, size_t ws_size,
                              hipStream_t stream)
{
  (void)in_sizes; (void)n_in; (void)out_size; (void)ws_size;
  const float* x        = (const float*)d_in[0];
  const float* in_w     = (const float*)d_in[1];
  const float* conv_w   = (const float*)d_in[2];
  const float* conv_b   = (const float*)d_in[3];
  const float* xproj_w  = (const float*)d_in[4];
  const float* dtproj_w = (const float*)d_in[5];
  const float* dtproj_b = (const float*)d_in[6];
  const float* A_log    = (const float*)d_in[7];
  const float* Dp       = (const float*)d_in[8];
  const float* out_w    = (const float*)d_in[9];

  char* base = (char*)d_ws;
  const size_t MiB = 1024*1024;
  // Region 0 [0,64 MiB): xi_bf(32) [p1] -> part(16) [dt] -> delta_bf(32) [e+scan]
  bf16*  xi_bf = (bf16*) (base + 0);
  float* part  = (float*)(base + 0);          // 8*8192*64*4 = 16 MiB
  bf16*  dl_bf = (bf16*) (base + 0);          // delta, 32 MiB
  bf16*  x_bf  = (bf16*) (base + 32*MiB);     // 16 MiB
  bf16*  w1_bf = (bf16*) (base + 48*MiB);     // 8 MiB
  bf16*  g_bf  = (bf16*) (base + 64*MiB);     // 32 MiB
  bf16*  u_bf  = (bf16*) (base + 96*MiB);     // 32 MiB
  bf16*  y_bf  = (bf16*) (base + 128*MiB);    // 32 MiB
  bf16*  wo_bf = (bf16*) (base + 160*MiB);    // 4 MiB
  bf16*  xp_bf = (bf16*) (base + 164*MiB);    // 0.25 MiB
  bf16*  dp_bf = (bf16*) (base + 165*MiB);    // 0.25 MiB
  bf16*  dtl_bf= (bf16*) (base + 166*MiB);    // 1 MiB
  float* P     = (float*)(base + 167*MiB);    // 1 MiB
  float* F     = (float*)(base + 168*MiB);    // 1 MiB
  float* Sin   = (float*)(base + 169*MiB);    // 1 MiB  -> total 170 MiB (fits)

  // fused cvt: x, in_proj_w, x_proj_w, dt_proj_w, out_proj_w (float4 counts)
  const int c0 = (M_*DM_)/4, c1 = (2*DI_*DM_)/4, c2 = (DT_*DI_)/4,
            c3 = (DI_*DT_)/4, c4 = (DM_*DI_)/4;
  const int ctot = c0+c1+c2+c3+c4;
  cvt_all_kernel<<<(ctot+255)/256, 256, 0, stream>>>(
      (const float4*)x,        (bf16x4*)x_bf,  c0,
      (const float4*)in_w,     (bf16x4*)w1_bf, c1,
      (const float4*)xproj_w,  (bf16x4*)xp_bf, c2,
      (const float4*)dtproj_w, (bf16x4*)dp_bf, c3,
      (const float4*)out_w,    (bf16x4*)wo_bf, c4);

  // 1) xz = x @ in_proj_w^T ; split -> xi (bf16), g=silu(z) (bf16)
  gemm_bt<0><<<dim3((2*DI_)/128, M_/128), 256, 0, stream>>>(
      x_bf, w1_bf, M_, 2*DI_, DM_, nullptr, xi_bf, g_bf, nullptr);
  // 2) depthwise causal conv + bias + silu -> u (bf16)
  conv_silu_kernel<<<(M_*DI_)/256, 256, 0, stream>>>(xi_bf, conv_w, conv_b, u_bf);
  // 3) dt_low = u @ x_proj_w^T, split-K=8 -> fp32 partials (xi region now dead)
  gemm_bt<4><<<dim3(1, M_/128, KSPL), 256, 0, stream>>>(
      u_bf, xp_bf, M_, DT_, DI_, part, nullptr, nullptr, nullptr);
  dt_reduce_kernel<<<(M_*DT_)/256, 256, 0, stream>>>(part, dtl_bf);
  // 4) delta = clip(softplus(dtl @ dt_proj_w^T + b)) -> bf16 (R0 reuse)
  gemm_bt<2><<<dim3(DI_/128, M_/128), 256, 0, stream>>>(
      dtl_bf, dp_bf, M_, DI_, DT_, nullptr, dl_bf, nullptr, dtproj_b);
  // 5) chunked scan + skip + gate -> y (bf16)
  scan_pass1<<<dim3(DI_/256, G_, B_), 256, 0, stream>>>(dl_bf, u_bf, A_log, P, F);
  scan_pass2<<<(B_*DI_)/256, 256, 0, stream>>>(P, F, Sin);
  scan_pass3<<<dim3(DI_/256, G_, B_), 256, 0, stream>>>(dl_bf, u_bf, g_bf, Sin, A_log, Dp, y_bf);
  // 6) out = y @ out_proj_w^T  (fp32 output)
  gemm_bt<3><<<dim3(DM_/128, M_/128), 256, 0, stream>>>(
      y_bf, wo_bf, M_, DM_, DI_, (float*)d_out, nullptr, nullptr, nullptr);
}

// Round 6
// 433.416 us; speedup vs baseline: 1.3610x; 1.3610x over previous
//
#include <hip/hip_runtime.h>
#include <cstdint>
#include <cstddef>

#define B_   2
#define L_   4096
#define DM_  1024
#define DI_  2048
#define DT_  64
#define M_   (B_*L_)      // 8192 rows
#define G_   64           // scan chunks per row
#define CH_  (L_/G_)      // 64 elements per chunk
#define KSPL 8            // split-K factor for dt_low GEMM
#define KSL  (DI_/KSPL)   // 256 per split
#define BK_  32           // BK=64 measured REGRESSIVE (R4)
#define LDC  136          // C-stage LDS stride in bf16 (272B: 16B-aligned rows)
#define LDCF 68           // C-stage LDS stride in fp32 for EPI=4 (272B)
#define LDC3 132          // C-stage LDS stride in fp32 for EPI=3 (528B, 16B-aligned)

typedef __bf16 bf16;
typedef __bf16 bf16x8 __attribute__((ext_vector_type(8)));
typedef __bf16 bf16x4 __attribute__((ext_vector_type(4)));
typedef float  f32x4  __attribute__((ext_vector_type(4)));

__device__ __forceinline__ float silu_f(float x){ return x / (1.f + __expf(-x)); }
// hw-instruction softplus (v_exp_f32/v_log_f32); |err| << bf16 rounding
__device__ __forceinline__ float softplus_f(float x){
  return fmaxf(x, 0.f) + __logf(1.f + __expf(-fabsf(x)));
}

// async global->LDS, 16B per lane (m97). LDS dest = wave-uniform base + lane*16.
__device__ __forceinline__ void gl_lds16(const bf16* g, bf16* l){
  __builtin_amdgcn_global_load_lds(
      (const __attribute__((address_space(1))) void*)g,
      (__attribute__((address_space(3))) void*)l, 16, 0, 0);
}

// ---------------- fused fp32 -> bf16 conversion for all 5 weight/input tensors
__global__ __launch_bounds__(256)
void cvt_all_kernel(const float4* __restrict__ s0, bf16x4* __restrict__ d0, int n0,
                    const float4* __restrict__ s1, bf16x4* __restrict__ d1, int n1,
                    const float4* __restrict__ s2, bf16x4* __restrict__ d2, int n2,
                    const float4* __restrict__ s3, bf16x4* __restrict__ d3, int n3,
                    const float4* __restrict__ s4, bf16x4* __restrict__ d4, int n4)
{
  int i = blockIdx.x*256 + threadIdx.x;
  const float4* s; bf16x4* d;
  if      (i < n0)                 { s = s0; d = d0; }
  else if ((i -= n0) < n1)         { s = s1; d = d1; }
  else if ((i -= n1) < n2)         { s = s2; d = d2; }
  else if ((i -= n2) < n3)         { s = s3; d = d3; }
  else if ((i -= n3) < n4)         { s = s4; d = d4; }
  else return;
  float4 v = s[i];
  bf16x4 o = {(bf16)v.x, (bf16)v.y, (bf16)v.z, (bf16)v.w};
  d[i] = o;
}

// ---------------- GEMM: C[M,N] = A[M,K] * W[N,K]^T, bf16 MFMA ----------------
// m97 K-loop (BK=32, global_load_lds w16, unpadded staging LDS) + NEW
// LDS-transposed epilogue: C-layout scattered 2B stores measured at 188 GB/s
// effective (R5: gemm_bt<2> = 179us, MfmaUtil 0.5%). Now: acc -> LDS (padded
// stride) -> coalesced 16B/lane global stores.
// EPI: 0 = in_proj split (tile entirely xi or entirely g; g gets silu) bf16
//      2 = dt epilogue (softplus/clip -> delta bf16)
//      3 = plain fp32 store (final output), two 64-row LDS passes
//      4 = split-K partial fp32 (dt_low, N=64), K-range from blockIdx.z
template<int EPI>
__global__ __launch_bounds__(256)
void gemm_bt(const bf16* __restrict__ A, const bf16* __restrict__ W,
             int M, int N, int K,
             float* __restrict__ o0, bf16* __restrict__ ob, bf16* __restrict__ ob2,
             const float* __restrict__ bias)
{
  __shared__ char smem[34816];                 // As/Bs (16 KiB) reused as C-stage
  bf16* As = (bf16*)smem;
  bf16* Bs = (bf16*)(smem + 128*BK_*2);
  const int t    = threadIdx.x;
  const int lane = t & 63;
  const int wave = t >> 6;
  const int wm   = wave >> 1, wn = wave & 1;
  const int l16  = lane & 15, quad = lane >> 4;
  const int m0   = blockIdx.y * 128, n0 = blockIdx.x * 128;

  const int srow = (lane >> 2);        // staging: 0..15 within issue
  const int scol = (lane & 3) * 8;     // element col: 0,8,16,24

  f32x4 acc[4][4] = {};

  const int kbase   = (EPI == 4) ? (int)blockIdx.z * KSL : 0;
  const int kframes = (EPI == 4) ? (KSL / BK_) : (K / BK_);

  for (int kt = 0; kt < kframes; ++kt){
    const int k0 = kbase + kt * BK_;
    #pragma unroll
    for (int j = 0; j < 2; ++j){
      const int row16 = wave*32 + j*16;
      int rA = m0 + row16 + srow; if (rA >= M) rA = M - 1;
      int rB = n0 + row16 + srow; if (rB >= N) rB = N - 1;   // clamp for N<128
      gl_lds16(A + (size_t)rA*K + k0 + scol, &As[row16*BK_]);
      gl_lds16(W + (size_t)rB*K + k0 + scol, &Bs[row16*BK_]);
    }
    __syncthreads();
    bf16x8 af[4], bf_[4];
    #pragma unroll
    for (int i = 0; i < 4; ++i){
      af[i]  = *(const bf16x8*)&As[(wm*64 + i*16 + l16)*BK_ + quad*8];
      bf_[i] = *(const bf16x8*)&Bs[(wn*64 + i*16 + l16)*BK_ + quad*8];
    }
    #pragma unroll
    for (int mi = 0; mi < 4; ++mi)
      #pragma unroll
      for (int ni = 0; ni < 4; ++ni)
        acc[mi][ni] = __builtin_amdgcn_mfma_f32_16x16x32_bf16(af[mi], bf_[ni], acc[mi][ni], 0, 0, 0);
    __syncthreads();   // also releases As/Bs for C-stage reuse
  }

  // ---- epilogue. acc C/D layout (m89/m91): col = lane&15, row = quad*4 + reg
  if (EPI == 3){
    // fp32 full-width tile: two 64-row passes through 33 KiB LDS
    float* Cf = (float*)smem;
    #pragma unroll
    for (int pass = 0; pass < 2; ++pass){
      if (wm == pass){
        #pragma unroll
        for (int mi = 0; mi < 4; ++mi)
          #pragma unroll
          for (int ni = 0; ni < 4; ++ni)
            #pragma unroll
            for (int r = 0; r < 4; ++r)
              Cf[(mi*16 + quad*4 + r)*LDC3 + wn*64 + ni*16 + l16] = acc[mi][ni][r];
      }
      __syncthreads();
      #pragma unroll
      for (int it = 0; it < 8; ++it){
        const int row = it*8 + (t >> 5);
        const int c4  = (t & 31) * 4;
        float4 v = *(const float4*)&Cf[row*LDC3 + c4];
        *(float4*)&o0[(size_t)(m0 + pass*64 + row)*N + n0 + c4] = v;
      }
      __syncthreads();
    }
  } else if (EPI == 4){
    // fp32, N=64: only wn==0 columns valid
    float* Cf = (float*)smem;
    if (wn == 0){
      #pragma unroll
      for (int mi = 0; mi < 4; ++mi)
        #pragma unroll
        for (int ni = 0; ni < 4; ++ni)
          #pragma unroll
          for (int r = 0; r < 4; ++r)
            Cf[(wm*64 + mi*16 + quad*4 + r)*LDCF + ni*16 + l16] = acc[mi][ni][r];
    }
    __syncthreads();
    #pragma unroll
    for (int it = 0; it < 8; ++it){
      const int row = it*16 + (t >> 4);
      const int c4  = (t & 15) * 4;
      float4 v = *(const float4*)&Cf[row*LDCF + c4];
      *(float4*)&o0[((size_t)blockIdx.z*M_ + m0 + row)*DT_ + c4] = v;
    }
  } else {
    // bf16 outputs (EPI 0 / 2) via padded LDS stage
    bf16* Cs = (bf16*)smem;
    #pragma unroll
    for (int mi = 0; mi < 4; ++mi){
      #pragma unroll
      for (int ni = 0; ni < 4; ++ni){
        const int n = n0 + wn*64 + ni*16 + l16;
        #pragma unroll
        for (int r = 0; r < 4; ++r){
          float v = acc[mi][ni][r];
          if (EPI == 0){
            if (n0 >= DI_) v = silu_f(v);          // g half
          } else { // EPI == 2
            v = softplus_f(v + bias[n]);
            v = fminf(fmaxf(v, 1e-6f), 10.f);      // delta
          }
          Cs[(wm*64 + mi*16 + quad*4 + r)*LDC + wn*64 + ni*16 + l16] = (bf16)v;
        }
      }
    }
    __syncthreads();
    #pragma unroll
    for (int it = 0; it < 8; ++it){
      const int row = it*16 + (t >> 4);
      const int c8  = (t & 15) * 8;
      bf16x8 v = *(const bf16x8*)&Cs[row*LDC + c8];
      if (EPI == 0){
        if (n0 < DI_) *(bf16x8*)&ob [(size_t)(m0+row)*DI_ + n0        + c8] = v;
        else          *(bf16x8*)&ob2[(size_t)(m0+row)*DI_ + n0 - DI_  + c8] = v;
      } else {
        *(bf16x8*)&ob[(size_t)(m0+row)*N + n0 + c8] = v;
      }
    }
  }
}

// ---------------- split-K reduce: dtl = sum_z partial[z] (bf16) ----------------
__global__ __launch_bounds__(256)
void dt_reduce_kernel(const float* __restrict__ part, bf16* __restrict__ dtl){
  const int i = blockIdx.x*256 + threadIdx.x;   // m*DT + n
  float s = 0.f;
  #pragma unroll
  for (int z = 0; z < KSPL; ++z) s += part[(size_t)z*M_*DT_ + i];
  dtl[i] = (bf16)s;
}

// ---------------- depthwise causal conv (K=4) + bias + SiLU ----------------
__global__ __launch_bounds__(256)
void conv_silu_kernel(const bf16* __restrict__ xi, const float* __restrict__ cw,
                      const float* __restrict__ cb, bf16* __restrict__ ubf)
{
  const int idx = blockIdx.x*256 + threadIdx.x;    // (b,l,d) flat, coalesced in d
  const int d = idx & (DI_-1);
  const int l = (idx >> 11) & (L_-1);              // DI_=2^11, L_=2^12
  float s = cb[d];
  #pragma unroll
  for (int k = 0; k < 4; ++k){
    const int ll = l + k - 3;
    if (ll >= 0) s += (float)xi[idx + (k-3)*DI_] * cw[d*4 + k];
  }
  ubf[idx] = (bf16)silu_f(s);
}

// ---------------- selective scan: 3-pass chunked linear scan ----------------
__device__ __forceinline__ float e_of(float delta, float Ad){
  float ee = __expf(delta * Ad);
  return fminf(fmaxf(ee, 1e-6f), 1.f);
}
__device__ __forceinline__ float a_of(const float* alog, int d){
  float Ad = -__expf(alog[d]);
  return fminf(fmaxf(Ad, -10.f), -1e-6f);
}

__global__ __launch_bounds__(256)
void scan_pass1(const bf16* __restrict__ delta, const bf16* __restrict__ u,
                const float* __restrict__ alog,
                float* __restrict__ P, float* __restrict__ F)
{
  const int d = blockIdx.x*256 + threadIdx.x;
  const int c = blockIdx.y, b = blockIdx.z;
  const float Ad = a_of(alog, d);
  size_t base = ((size_t)(b*L_ + c*CH_))*DI_ + d;
  float p = 1.f, f = 0.f;
  for (int i = 0; i < CH_; ++i){
    float ee = e_of((float)delta[base + (size_t)i*DI_], Ad);
    float uu = (float)u[base + (size_t)i*DI_];
    f = f*ee + uu;
    p *= ee;
  }
  const size_t o = ((size_t)b*G_ + c)*DI_ + d;
  P[o] = p; F[o] = f;
}

__global__ __launch_bounds__(256)
void scan_pass2(const float* __restrict__ P, const float* __restrict__ F,
                float* __restrict__ Sin)
{
  const int idx = blockIdx.x*256 + threadIdx.x;    // b*DI + d
  const int d = idx & (DI_-1);
  const int b = idx >> 11;
  float s = 0.f;
  for (int c = 0; c < G_; ++c){
    const size_t o = ((size_t)b*G_ + c)*DI_ + d;
    Sin[o] = s;
    s = F[o] + P[o]*s;
  }
}

__global__ __launch_bounds__(256)
void scan_pass3(const bf16* __restrict__ delta, const bf16* __restrict__ u,
                const bf16* __restrict__ g, const float* __restrict__ Sin,
                const float* __restrict__ alog, const float* __restrict__ Dp,
                bf16* __restrict__ y)
{
  const int d = blockIdx.x*256 + threadIdx.x;
  const int c = blockIdx.y, b = blockIdx.z;
  const float Ad = a_of(alog, d);
  size_t base = ((size_t)(b*L_ + c*CH_))*DI_ + d;
  float s = Sin[((size_t)b*G_ + c)*DI_ + d];
  const float Dd = Dp[d];
  for (int i = 0; i < CH_; ++i){
    const size_t idx = base + (size_t)i*DI_;
    const float uu = (float)u[idx];
    s = s*e_of((float)delta[idx], Ad) + uu;
    float yy = s + uu*Dd;
    yy = fminf(fmaxf(yy, -1e4f), 1e4f);
    yy *= (float)g[idx];              // g = silu(z), from GEMM1 epilogue
    y[idx] = (bf16)yy;
  }
}

// ---------------- host launch ----------------
extern "C" void kernel_launch(void* const* d_in, const int* in_sizes, int n_in,
                              void* d_out, int out_size, void* d_ws, size_t ws_size,
                              hipStream_t stream)
{
  (void)in_sizes; (void)n_in; (void)out_size; (void)ws_size;
  const float* x        = (const float*)d_in[0];
  const float* in_w     = (const float*)d_in[1];
  const float* conv_w   = (const float*)d_in[2];
  const float* conv_b   = (const float*)d_in[3];
  const float* xproj_w  = (const float*)d_in[4];
  const float* dtproj_w = (const float*)d_in[5];
  const float* dtproj_b = (const float*)d_in[6];
  const float* A_log    = (const float*)d_in[7];
  const float* Dp       = (const float*)d_in[8];
  const float* out_w    = (const float*)d_in[9];

  char* base = (char*)d_ws;
  const size_t MiB = 1024*1024;
  // Region 0 [0,64 MiB): xi_bf(32) [p1] -> part(16) [dt] -> delta_bf(32) [e+scan]
  bf16*  xi_bf = (bf16*) (base + 0);
  float* part  = (float*)(base + 0);          // 8*8192*64*4 = 16 MiB
  bf16*  dl_bf = (bf16*) (base + 0);          // delta, 32 MiB
  bf16*  x_bf  = (bf16*) (base + 32*MiB);     // 16 MiB
  bf16*  w1_bf = (bf16*) (base + 48*MiB);     // 8 MiB
  bf16*  g_bf  = (bf16*) (base + 64*MiB);     // 32 MiB
  bf16*  u_bf  = (bf16*) (base + 96*MiB);     // 32 MiB
  bf16*  y_bf  = (bf16*) (base + 128*MiB);    // 32 MiB
  bf16*  wo_bf = (bf16*) (base + 160*MiB);    // 4 MiB
  bf16*  xp_bf = (bf16*) (base + 164*MiB);    // 0.25 MiB
  bf16*  dp_bf = (bf16*) (base + 165*MiB);    // 0.25 MiB
  bf16*  dtl_bf= (bf16*) (base + 166*MiB);    // 1 MiB
  float* P     = (float*)(base + 167*MiB);    // 1 MiB
  float* F     = (float*)(base + 168*MiB);    // 1 MiB
  float* Sin   = (float*)(base + 169*MiB);    // 1 MiB  -> total 170 MiB (fits)

  const int c0 = (M_*DM_)/4, c1 = (2*DI_*DM_)/4, c2 = (DT_*DI_)/4,
            c3 = (DI_*DT_)/4, c4 = (DM_*DI_)/4;
  const int ctot = c0+c1+c2+c3+c4;
  cvt_all_kernel<<<(ctot+255)/256, 256, 0, stream>>>(
      (const float4*)x,        (bf16x4*)x_bf,  c0,
      (const float4*)in_w,     (bf16x4*)w1_bf, c1,
      (const float4*)xproj_w,  (bf16x4*)xp_bf, c2,
      (const float4*)dtproj_w, (bf16x4*)dp_bf, c3,
      (const float4*)out_w,    (bf16x4*)wo_bf, c4);

  // 1) xz = x @ in_proj_w^T ; split -> xi (bf16), g=silu(z) (bf16)
  gemm_bt<0><<<dim3((2*DI_)/128, M_/128), 256, 0, stream>>>(
      x_bf, w1_bf, M_, 2*DI_, DM_, nullptr, xi_bf, g_bf, nullptr);
  // 2) depthwise causal conv + bias + silu -> u (bf16)
  conv_silu_kernel<<<(M_*DI_)/256, 256, 0, stream>>>(xi_bf, conv_w, conv_b, u_bf);
  // 3) dt_low = u @ x_proj_w^T, split-K=8 -> fp32 partials (xi region now dead)
  gemm_bt<4><<<dim3(1, M_/128, KSPL), 256, 0, stream>>>(
      u_bf, xp_bf, M_, DT_, DI_, part, nullptr, nullptr, nullptr);
  dt_reduce_kernel<<<(M_*DT_)/256, 256, 0, stream>>>(part, dtl_bf);
  // 4) delta = clip(softplus(dtl @ dt_proj_w^T + b)) -> bf16 (R0 reuse)
  gemm_bt<2><<<dim3(DI_/128, M_/128), 256, 0, stream>>>(
      dtl_bf, dp_bf, M_, DI_, DT_, nullptr, dl_bf, nullptr, dtproj_b);
  // 5) chunked scan + skip + gate -> y (bf16)
  scan_pass1<<<dim3(DI_/256, G_, B_), 256, 0, stream>>>(dl_bf, u_bf, A_log, P, F);
  scan_pass2<<<(B_*DI_)/256, 256, 0, stream>>>(P, F, Sin);
  scan_pass3<<<dim3(DI_/256, G_, B_), 256, 0, stream>>>(dl_bf, u_bf, g_bf, Sin, A_log, Dp, y_bf);
  // 6) out = y @ out_proj_w^T  (fp32 output)
  gemm_bt<3><<<dim3(DM_/128, M_/128), 256, 0, stream>>>(
      y_bf, wo_bf, M_, DM_, DI_, (float*)d_out, nullptr, nullptr, nullptr);
}

// Round 7
// 428.410 us; speedup vs baseline: 1.3769x; 1.0117x over previous
//
#include <hip/hip_runtime.h>
#include <cstdint>
#include <cstddef>

#define B_   2
#define L_   4096
#define DM_  1024
#define DI_  2048
#define DT_  64
#define M_   (B_*L_)      // 8192 rows
#define G_   64           // scan chunks per row
#define CH_  (L_/G_)      // 64 elements per chunk
#define KSPL 8            // split-K factor for dt_low GEMM
#define KSL  (DI_/KSPL)   // 256 per split
#define BK_  32           // BK=64 measured REGRESSIVE (R4)
#define LDC  136          // C-stage LDS stride in bf16 (272B: 16B-aligned rows)
#define LDCF 68           // C-stage LDS stride in fp32 for EPI=4 (272B)
#define LDC3 132          // C-stage LDS stride in fp32 for EPI=3 (528B, 16B-aligned)

typedef __bf16 bf16;
typedef __bf16 bf16x8 __attribute__((ext_vector_type(8)));
typedef __bf16 bf16x4 __attribute__((ext_vector_type(4)));
typedef float  f32x4  __attribute__((ext_vector_type(4)));

__device__ __forceinline__ float silu_f(float x){ return x / (1.f + __expf(-x)); }
// hw-instruction softplus (v_exp_f32/v_log_f32); |err| << bf16 rounding
__device__ __forceinline__ float softplus_f(float x){
  return fmaxf(x, 0.f) + __logf(1.f + __expf(-fabsf(x)));
}
__device__ __forceinline__ float e_of(float delta, float Ad){
  float ee = __expf(delta * Ad);
  return fminf(fmaxf(ee, 1e-6f), 1.f);
}
__device__ __forceinline__ float a_of(const float* alog, int d){
  float Ad = -__expf(alog[d]);
  return fminf(fmaxf(Ad, -10.f), -1e-6f);
}

// async global->LDS, 16B per lane (m97). LDS dest = wave-uniform base + lane*16.
__device__ __forceinline__ void gl_lds16(const bf16* g, bf16* l){
  __builtin_amdgcn_global_load_lds(
      (const __attribute__((address_space(1))) void*)g,
      (__attribute__((address_space(3))) void*)l, 16, 0, 0);
}

// ---------------- fused fp32 -> bf16 conversion for all 5 weight/input tensors
__global__ __launch_bounds__(256)
void cvt_all_kernel(const float4* __restrict__ s0, bf16x4* __restrict__ d0, int n0,
                    const float4* __restrict__ s1, bf16x4* __restrict__ d1, int n1,
                    const float4* __restrict__ s2, bf16x4* __restrict__ d2, int n2,
                    const float4* __restrict__ s3, bf16x4* __restrict__ d3, int n3,
                    const float4* __restrict__ s4, bf16x4* __restrict__ d4, int n4)
{
  int i = blockIdx.x*256 + threadIdx.x;
  const float4* s; bf16x4* d;
  if      (i < n0)                 { s = s0; d = d0; }
  else if ((i -= n0) < n1)         { s = s1; d = d1; }
  else if ((i -= n1) < n2)         { s = s2; d = d2; }
  else if ((i -= n2) < n3)         { s = s3; d = d3; }
  else if ((i -= n3) < n4)         { s = s4; d = d4; }
  else return;
  float4 v = s[i];
  bf16x4 o = {(bf16)v.x, (bf16)v.y, (bf16)v.z, (bf16)v.w};
  d[i] = o;
}

// ---------------- GEMM: C[M,N] = A[M,K] * W[N,K]^T, bf16 MFMA ----------------
// m97 K-loop (BK=32, global_load_lds w16, unpadded staging LDS) + LDS-staged
// coalesced epilogue (R5->R6: 179us -> off top-5 for the delta GEMM).
// EPI: 0 = in_proj split (tile entirely xi or entirely g; g gets silu) bf16
//      2 = dt epilogue (softplus/clip -> delta bf16) + FUSED scan pass1:
//          tile = 2 chunks x 128 d; computes P,F from LDS delta + global u
//      3 = plain fp32 store (final output), two 64-row LDS passes
//      4 = split-K partial fp32 (dt_low, N=64), K-range from blockIdx.z
template<int EPI>
__global__ __launch_bounds__(256)
void gemm_bt(const bf16* __restrict__ A, const bf16* __restrict__ W,
             int M, int N, int K,
             float* __restrict__ o0, bf16* __restrict__ ob, bf16* __restrict__ ob2,
             const float* __restrict__ bias, const float* __restrict__ alog,
             const bf16* __restrict__ uq, float* __restrict__ Pq,
             float* __restrict__ Fq)
{
  __shared__ char smem[34816];                 // As/Bs (16 KiB) reused as C-stage
  bf16* As = (bf16*)smem;
  bf16* Bs = (bf16*)(smem + 128*BK_*2);
  const int t    = threadIdx.x;
  const int lane = t & 63;
  const int wave = t >> 6;
  const int wm   = wave >> 1, wn = wave & 1;
  const int l16  = lane & 15, quad = lane >> 4;
  const int m0   = blockIdx.y * 128, n0 = blockIdx.x * 128;

  const int srow = (lane >> 2);        // staging: 0..15 within issue
  const int scol = (lane & 3) * 8;     // element col: 0,8,16,24

  f32x4 acc[4][4] = {};

  const int kbase   = (EPI == 4) ? (int)blockIdx.z * KSL : 0;
  const int kframes = (EPI == 4) ? (KSL / BK_) : (K / BK_);

  for (int kt = 0; kt < kframes; ++kt){
    const int k0 = kbase + kt * BK_;
    #pragma unroll
    for (int j = 0; j < 2; ++j){
      const int row16 = wave*32 + j*16;
      int rA = m0 + row16 + srow; if (rA >= M) rA = M - 1;
      int rB = n0 + row16 + srow; if (rB >= N) rB = N - 1;   // clamp for N<128
      gl_lds16(A + (size_t)rA*K + k0 + scol, &As[row16*BK_]);
      gl_lds16(W + (size_t)rB*K + k0 + scol, &Bs[row16*BK_]);
    }
    __syncthreads();
    bf16x8 af[4], bf_[4];
    #pragma unroll
    for (int i = 0; i < 4; ++i){
      af[i]  = *(const bf16x8*)&As[(wm*64 + i*16 + l16)*BK_ + quad*8];
      bf_[i] = *(const bf16x8*)&Bs[(wn*64 + i*16 + l16)*BK_ + quad*8];
    }
    #pragma unroll
    for (int mi = 0; mi < 4; ++mi)
      #pragma unroll
      for (int ni = 0; ni < 4; ++ni)
        acc[mi][ni] = __builtin_amdgcn_mfma_f32_16x16x32_bf16(af[mi], bf_[ni], acc[mi][ni], 0, 0, 0);
    __syncthreads();   // also releases As/Bs for C-stage reuse
  }

  // ---- epilogue. acc C/D layout (m89/m91): col = lane&15, row = quad*4 + reg
  if (EPI == 3){
    // fp32 full-width tile: two 64-row passes through 33 KiB LDS
    float* Cf = (float*)smem;
    #pragma unroll
    for (int pass = 0; pass < 2; ++pass){
      if (wm == pass){
        #pragma unroll
        for (int mi = 0; mi < 4; ++mi)
          #pragma unroll
          for (int ni = 0; ni < 4; ++ni)
            #pragma unroll
            for (int r = 0; r < 4; ++r)
              Cf[(mi*16 + quad*4 + r)*LDC3 + wn*64 + ni*16 + l16] = acc[mi][ni][r];
      }
      __syncthreads();
      #pragma unroll
      for (int it = 0; it < 8; ++it){
        const int row = it*8 + (t >> 5);
        const int c4  = (t & 31) * 4;
        float4 v = *(const float4*)&Cf[row*LDC3 + c4];
        *(float4*)&o0[(size_t)(m0 + pass*64 + row)*N + n0 + c4] = v;
      }
      __syncthreads();
    }
  } else if (EPI == 4){
    // fp32, N=64: only wn==0 columns valid
    float* Cf = (float*)smem;
    if (wn == 0){
      #pragma unroll
      for (int mi = 0; mi < 4; ++mi)
        #pragma unroll
        for (int ni = 0; ni < 4; ++ni)
          #pragma unroll
          for (int r = 0; r < 4; ++r)
            Cf[(wm*64 + mi*16 + quad*4 + r)*LDCF + ni*16 + l16] = acc[mi][ni][r];
    }
    __syncthreads();
    #pragma unroll
    for (int it = 0; it < 8; ++it){
      const int row = it*16 + (t >> 4);
      const int c4  = (t & 15) * 4;
      float4 v = *(const float4*)&Cf[row*LDCF + c4];
      *(float4*)&o0[((size_t)blockIdx.z*M_ + m0 + row)*DT_ + c4] = v;
    }
  } else {
    // bf16 outputs (EPI 0 / 2) via padded LDS stage
    bf16* Cs = (bf16*)smem;
    #pragma unroll
    for (int mi = 0; mi < 4; ++mi){
      #pragma unroll
      for (int ni = 0; ni < 4; ++ni){
        const int n = n0 + wn*64 + ni*16 + l16;
        #pragma unroll
        for (int r = 0; r < 4; ++r){
          float v = acc[mi][ni][r];
          if (EPI == 0){
            if (n0 >= DI_) v = silu_f(v);          // g half
          } else { // EPI == 2
            v = softplus_f(v + bias[n]);
            v = fminf(fmaxf(v, 1e-6f), 10.f);      // delta
          }
          Cs[(wm*64 + mi*16 + quad*4 + r)*LDC + wn*64 + ni*16 + l16] = (bf16)v;
        }
      }
    }
    __syncthreads();
    #pragma unroll
    for (int it = 0; it < 8; ++it){
      const int row = it*16 + (t >> 4);
      const int c8  = (t & 15) * 8;
      bf16x8 v = *(const bf16x8*)&Cs[row*LDC + c8];
      if (EPI == 0){
        if (n0 < DI_) *(bf16x8*)&ob [(size_t)(m0+row)*DI_ + n0        + c8] = v;
        else          *(bf16x8*)&ob2[(size_t)(m0+row)*DI_ + n0 - DI_  + c8] = v;
      } else {
        *(bf16x8*)&ob[(size_t)(m0+row)*N + n0 + c8] = v;
      }
    }
    if (EPI == 2){
      // ---- fused scan pass1: tile rows = chunks {c0, c0+1} of batch b.
      // Uses bf16-rounded delta from LDS (identical to what pass3 reads) ->
      // results bit-identical to the former standalone pass1.
      const int chunk = t >> 7;            // 0..1
      const int dcol  = t & 127;           // 0..127
      const int dglob = n0 + dcol;
      const float Ad  = a_of(alog, dglob);
      const int b  = m0 >> 12;             // 4096 rows per batch
      const int c0 = (m0 & 4095) >> 6;     // within-batch chunk of tile row 0
      const size_t ubase = (size_t)(m0 + chunk*64)*DI_ + dglob;
      float p = 1.f, f = 0.f;
      for (int i = 0; i < CH_; ++i){
        float dl = (float)Cs[(chunk*64 + i)*LDC + dcol];
        float ee = e_of(dl, Ad);
        float uu = (float)uq[ubase + (size_t)i*DI_];
        f = f*ee + uu;
        p *= ee;
      }
      const size_t o = ((size_t)(b*G_ + c0 + chunk))*DI_ + dglob;
      Pq[o] = p; Fq[o] = f;
    }
  }
}

// ---------------- split-K reduce: dtl = sum_z partial[z] (bf16) ----------------
__global__ __launch_bounds__(256)
void dt_reduce_kernel(const float* __restrict__ part, bf16* __restrict__ dtl){
  const int i = blockIdx.x*256 + threadIdx.x;   // m*DT + n
  float s = 0.f;
  #pragma unroll
  for (int z = 0; z < KSPL; ++z) s += part[(size_t)z*M_*DT_ + i];
  dtl[i] = (bf16)s;
}

// ---------------- depthwise causal conv (K=4) + bias + SiLU ----------------
__global__ __launch_bounds__(256)
void conv_silu_kernel(const bf16* __restrict__ xi, const float* __restrict__ cw,
                      const float* __restrict__ cb, bf16* __restrict__ ubf)
{
  const int idx = blockIdx.x*256 + threadIdx.x;    // (b,l,d) flat, coalesced in d
  const int d = idx & (DI_-1);
  const int l = (idx >> 11) & (L_-1);              // DI_=2^11, L_=2^12
  float s = cb[d];
  #pragma unroll
  for (int k = 0; k < 4; ++k){
    const int ll = l + k - 3;
    if (ll >= 0) s += (float)xi[idx + (k-3)*DI_] * cw[d*4 + k];
  }
  ubf[idx] = (bf16)silu_f(s);
}

// ---------------- scan pass3 (with inlined pass2 prefix) ----------------
// Per (d-slice, chunk c, b): prefix-combine P,F over chunks 0..c-1 (P,F are
// 2 MiB -> L2-resident; <=63 dependent FMAs), then reconstruct states within
// the chunk and apply skip + gate. Bit-identical to former pass2+pass3.
__global__ __launch_bounds__(256)
void scan_pass3(const bf16* __restrict__ delta, const bf16* __restrict__ u,
                const bf16* __restrict__ g, const float* __restrict__ P,
                const float* __restrict__ F, const float* __restrict__ alog,
                const float* __restrict__ Dp, bf16* __restrict__ y)
{
  const int d = blockIdx.x*256 + threadIdx.x;
  const int c = blockIdx.y, b = blockIdx.z;
  const float Ad = a_of(alog, d);
  float s = 0.f;
  for (int cc = 0; cc < c; ++cc){
    const size_t o = ((size_t)(b*G_ + cc))*DI_ + d;
    s = F[o] + P[o]*s;
  }
  size_t base = ((size_t)(b*L_ + c*CH_))*DI_ + d;
  const float Dd = Dp[d];
  for (int i = 0; i < CH_; ++i){
    const size_t idx = base + (size_t)i*DI_;
    const float uu = (float)u[idx];
    s = s*e_of((float)delta[idx], Ad) + uu;
    float yy = s + uu*Dd;
    yy = fminf(fmaxf(yy, -1e4f), 1e4f);
    yy *= (float)g[idx];              // g = silu(z), from GEMM1 epilogue
    y[idx] = (bf16)yy;
  }
}

// ---------------- host launch ----------------
extern "C" void kernel_launch(void* const* d_in, const int* in_sizes, int n_in,
                              void* d_out, int out_size, void* d_ws, size_t ws_size,
                              hipStream_t stream)
{
  (void)in_sizes; (void)n_in; (void)out_size; (void)ws_size;
  const float* x        = (const float*)d_in[0];
  const float* in_w     = (const float*)d_in[1];
  const float* conv_w   = (const float*)d_in[2];
  const float* conv_b   = (const float*)d_in[3];
  const float* xproj_w  = (const float*)d_in[4];
  const float* dtproj_w = (const float*)d_in[5];
  const float* dtproj_b = (const float*)d_in[6];
  const float* A_log    = (const float*)d_in[7];
  const float* Dp       = (const float*)d_in[8];
  const float* out_w    = (const float*)d_in[9];

  char* base = (char*)d_ws;
  const size_t MiB = 1024*1024;
  // Region 0 [0,64 MiB): xi_bf(32) [p1] -> part(16) [dt] -> delta_bf(32) [e+scan]
  bf16*  xi_bf = (bf16*) (base + 0);
  float* part  = (float*)(base + 0);          // 8*8192*64*4 = 16 MiB
  bf16*  dl_bf = (bf16*) (base + 0);          // delta, 32 MiB
  bf16*  x_bf  = (bf16*) (base + 32*MiB);     // 16 MiB
  bf16*  w1_bf = (bf16*) (base + 48*MiB);     // 8 MiB
  bf16*  g_bf  = (bf16*) (base + 64*MiB);     // 32 MiB
  bf16*  u_bf  = (bf16*) (base + 96*MiB);     // 32 MiB
  bf16*  y_bf  = (bf16*) (base + 128*MiB);    // 32 MiB
  bf16*  wo_bf = (bf16*) (base + 160*MiB);    // 4 MiB
  bf16*  xp_bf = (bf16*) (base + 164*MiB);    // 0.25 MiB
  bf16*  dp_bf = (bf16*) (base + 165*MiB);    // 0.25 MiB
  bf16*  dtl_bf= (bf16*) (base + 166*MiB);    // 1 MiB
  float* P     = (float*)(base + 167*MiB);    // 1 MiB
  float* F     = (float*)(base + 168*MiB);    // 1 MiB  -> total 169 MiB (fits)

  const int c0 = (M_*DM_)/4, c1 = (2*DI_*DM_)/4, c2 = (DT_*DI_)/4,
            c3 = (DI_*DT_)/4, c4 = (DM_*DI_)/4;
  const int ctot = c0+c1+c2+c3+c4;
  cvt_all_kernel<<<(ctot+255)/256, 256, 0, stream>>>(
      (const float4*)x,        (bf16x4*)x_bf,  c0,
      (const float4*)in_w,     (bf16x4*)w1_bf, c1,
      (const float4*)xproj_w,  (bf16x4*)xp_bf, c2,
      (const float4*)dtproj_w, (bf16x4*)dp_bf, c3,
      (const float4*)out_w,    (bf16x4*)wo_bf, c4);

  // 1) xz = x @ in_proj_w^T ; split -> xi (bf16), g=silu(z) (bf16)
  gemm_bt<0><<<dim3((2*DI_)/128, M_/128), 256, 0, stream>>>(
      x_bf, w1_bf, M_, 2*DI_, DM_, nullptr, xi_bf, g_bf, nullptr,
      nullptr, nullptr, nullptr, nullptr);
  // 2) depthwise causal conv + bias + silu -> u (bf16)
  conv_silu_kernel<<<(M_*DI_)/256, 256, 0, stream>>>(xi_bf, conv_w, conv_b, u_bf);
  // 3) dt_low = u @ x_proj_w^T, split-K=8 -> fp32 partials (xi region now dead)
  gemm_bt<4><<<dim3(1, M_/128, KSPL), 256, 0, stream>>>(
      u_bf, xp_bf, M_, DT_, DI_, part, nullptr, nullptr, nullptr,
      nullptr, nullptr, nullptr, nullptr);
  dt_reduce_kernel<<<(M_*DT_)/256, 256, 0, stream>>>(part, dtl_bf);
  // 4) delta = clip(softplus(dtl @ dt_proj_w^T + b)) -> bf16 + fused scan pass1
  gemm_bt<2><<<dim3(DI_/128, M_/128), 256, 0, stream>>>(
      dtl_bf, dp_bf, M_, DI_, DT_, nullptr, dl_bf, nullptr, dtproj_b,
      A_log, u_bf, P, F);
  // 5) scan: prefix from P,F + within-chunk states + skip + gate -> y (bf16)
  scan_pass3<<<dim3(DI_/256, G_, B_), 256, 0, stream>>>(
      dl_bf, u_bf, g_bf, P, F, A_log, Dp, y_bf);
  // 6) out = y @ out_proj_w^T  (fp32 output)
  gemm_bt<3><<<dim3(DM_/128, M_/128), 256, 0, stream>>>(
      y_bf, wo_bf, M_, DM_, DI_, (float*)d_out, nullptr, nullptr, nullptr,
      nullptr, nullptr, nullptr, nullptr);
}

// Round 8
// 417.793 us; speedup vs baseline: 1.4119x; 1.0254x over previous
//
#include <hip/hip_runtime.h>
#include <cstdint>
#include <cstddef>

#define B_   2
#define L_   4096
#define DM_  1024
#define DI_  2048
#define DT_  64
#define M_   (B_*L_)      // 8192 rows
#define G_   64           // scan chunks per row
#define CH_  (L_/G_)      // 64 elements per chunk
#define KSPL 8            // split-K factor for dt_low GEMM
#define KSL  (DI_/KSPL)   // 256 per split
#define BK_  32           // BK=64 measured REGRESSIVE (R4)
#define LDC  136          // C-stage LDS stride in bf16 (272B: 16B-aligned rows)
#define LDCF 68           // C-stage LDS stride in fp32 for EPI=4 (272B)
#define LDC3 132          // C-stage LDS stride in fp32 for EPI=3 (528B, 16B-aligned)

typedef __bf16 bf16;
typedef __bf16 bf16x8 __attribute__((ext_vector_type(8)));
typedef __bf16 bf16x4 __attribute__((ext_vector_type(4)));
typedef float  f32x4  __attribute__((ext_vector_type(4)));

__device__ __forceinline__ float silu_f(float x){ return x / (1.f + __expf(-x)); }
// hw-instruction softplus (v_exp_f32/v_log_f32); |err| << bf16 rounding
__device__ __forceinline__ float softplus_f(float x){
  return fmaxf(x, 0.f) + __logf(1.f + __expf(-fabsf(x)));
}
__device__ __forceinline__ float e_of(float delta, float Ad){
  float ee = __expf(delta * Ad);
  return fminf(fmaxf(ee, 1e-6f), 1.f);
}
__device__ __forceinline__ float a_of(const float* alog, int d){
  float Ad = -__expf(alog[d]);
  return fminf(fmaxf(Ad, -10.f), -1e-6f);
}

// async global->LDS, 16B per lane (m97). LDS dest = wave-uniform base + lane*16.
__device__ __forceinline__ void gl_lds16(const bf16* g, bf16* l){
  __builtin_amdgcn_global_load_lds(
      (const __attribute__((address_space(1))) void*)g,
      (__attribute__((address_space(3))) void*)l, 16, 0, 0);
}

// ---------------- fused fp32 -> bf16 conversion for all 5 weight/input tensors
__global__ __launch_bounds__(256)
void cvt_all_kernel(const float4* __restrict__ s0, bf16x4* __restrict__ d0, int n0,
                    const float4* __restrict__ s1, bf16x4* __restrict__ d1, int n1,
                    const float4* __restrict__ s2, bf16x4* __restrict__ d2, int n2,
                    const float4* __restrict__ s3, bf16x4* __restrict__ d3, int n3,
                    const float4* __restrict__ s4, bf16x4* __restrict__ d4, int n4)
{
  int i = blockIdx.x*256 + threadIdx.x;
  const float4* s; bf16x4* d;
  if      (i < n0)                 { s = s0; d = d0; }
  else if ((i -= n0) < n1)         { s = s1; d = d1; }
  else if ((i -= n1) < n2)         { s = s2; d = d2; }
  else if ((i -= n2) < n3)         { s = s3; d = d3; }
  else if ((i -= n3) < n4)         { s = s4; d = d4; }
  else return;
  float4 v = s[i];
  bf16x4 o = {(bf16)v.x, (bf16)v.y, (bf16)v.z, (bf16)v.w};
  d[i] = o;
}

// ---------------- GEMM: C[M,N] = A[M,K] * W[N,K]^T, bf16 MFMA ----------------
// m97 K-loop (BK=32, global_load_lds w16, unpadded staging LDS) + LDS-staged
// coalesced epilogue. R8: M/N/K are TEMPLATE constants (R7 evidence: VALUBusy
// 57% vs MfmaUtil 25% -> per-iter 64-bit address recomputation is the issue
// limiter); staging uses 4 pointer-increment streams; group-of-4 m-tile
// swizzle for L2 reuse of the W stripe.
// EPI: 0 = in_proj split (tile entirely xi or entirely g; g gets silu) bf16
//      2 = dt epilogue (softplus/clip -> delta bf16) + FUSED scan pass1
//      3 = plain fp32 store (final output), two 64-row LDS passes
//      4 = split-K partial fp32 (dt_low, N=64), K-slice from blockIdx.z
template<int EPI, int MT, int NT, int KT>
__global__ __launch_bounds__(256)
void gemm_bt(const bf16* __restrict__ A, const bf16* __restrict__ W,
             float* __restrict__ o0, bf16* __restrict__ ob, bf16* __restrict__ ob2,
             const float* __restrict__ bias, const float* __restrict__ alog,
             const bf16* __restrict__ uq, float* __restrict__ Pq,
             float* __restrict__ Fq)
{
  __shared__ char smem[34816];                 // As/Bs (16 KiB) reused as C-stage
  bf16* As = (bf16*)smem;
  bf16* Bs = (bf16*)(smem + 128*BK_*2);
  const int t    = threadIdx.x;
  const int lane = t & 63;
  const int wave = t >> 6;
  const int wm   = wave >> 1, wn = wave & 1;
  const int l16  = lane & 15, quad = lane >> 4;

  // block swizzle: groups of 4 m-tiles iterate n together (W-stripe L2 reuse)
  int m0, n0;
  if (EPI == 4){
    m0 = blockIdx.y * 128; n0 = 0;
  } else {
    const int gx  = NT / 128;
    const int lin = blockIdx.y * gx + blockIdx.x;
    const int grp = lin / (gx * 4);
    const int rem = lin % (gx * 4);
    m0 = (grp * 4 + (rem & 3)) * 128;
    n0 = (rem >> 2) * 128;
  }

  const int srow = (lane >> 2);        // staging: 0..15 within issue
  const int scol = (lane & 3) * 8;     // element col: 0,8,16,24

  // full K stride for A/W rows (EPI4 slices K via kbase)
  const int KFULL = (EPI == 4) ? (KT * KSPL) : KT;
  const int kbase = (EPI == 4) ? (int)blockIdx.z * KT : 0;

  // pointer-increment staging streams (no per-iter 64-bit recompute)
  const int rowA0 = m0 + wave*32 + srow;
  int rB0 = n0 + wave*32 + srow, rB1 = rB0 + 16;
  if (NT < 128){ rB0 = (rB0 >= NT) ? NT-1 : rB0; rB1 = (rB1 >= NT) ? NT-1 : rB1; }
  const bf16* ap0 = A + (size_t)rowA0*KFULL        + kbase + scol;
  const bf16* ap1 = A + (size_t)(rowA0+16)*KFULL   + kbase + scol;
  const bf16* bp0 = W + (size_t)rB0*KFULL          + kbase + scol;
  const bf16* bp1 = W + (size_t)rB1*KFULL          + kbase + scol;
  bf16* lA0 = &As[(wave*32)*BK_];
  bf16* lA1 = &As[(wave*32+16)*BK_];
  bf16* lB0 = &Bs[(wave*32)*BK_];
  bf16* lB1 = &Bs[(wave*32+16)*BK_];

  f32x4 acc[4][4] = {};
  constexpr int kframes = KT / BK_;

  for (int kt = 0; kt < kframes; ++kt){
    gl_lds16(ap0, lA0);  gl_lds16(ap1, lA1);
    gl_lds16(bp0, lB0);  gl_lds16(bp1, lB1);
    ap0 += BK_; ap1 += BK_; bp0 += BK_; bp1 += BK_;
    __syncthreads();
    bf16x8 af[4], bf_[4];
    #pragma unroll
    for (int i = 0; i < 4; ++i){
      af[i]  = *(const bf16x8*)&As[(wm*64 + i*16 + l16)*BK_ + quad*8];
      bf_[i] = *(const bf16x8*)&Bs[(wn*64 + i*16 + l16)*BK_ + quad*8];
    }
    #pragma unroll
    for (int mi = 0; mi < 4; ++mi)
      #pragma unroll
      for (int ni = 0; ni < 4; ++ni)
        acc[mi][ni] = __builtin_amdgcn_mfma_f32_16x16x32_bf16(af[mi], bf_[ni], acc[mi][ni], 0, 0, 0);
    __syncthreads();   // also releases As/Bs for C-stage reuse
  }

  // ---- epilogue. acc C/D layout (m89/m91): col = lane&15, row = quad*4 + reg
  if (EPI == 3){
    // fp32 full-width tile: two 64-row passes through 33 KiB LDS
    float* Cf = (float*)smem;
    #pragma unroll
    for (int pass = 0; pass < 2; ++pass){
      if (wm == pass){
        #pragma unroll
        for (int mi = 0; mi < 4; ++mi)
          #pragma unroll
          for (int ni = 0; ni < 4; ++ni)
            #pragma unroll
            for (int r = 0; r < 4; ++r)
              Cf[(mi*16 + quad*4 + r)*LDC3 + wn*64 + ni*16 + l16] = acc[mi][ni][r];
      }
      __syncthreads();
      #pragma unroll
      for (int it = 0; it < 8; ++it){
        const int row = it*8 + (t >> 5);
        const int c4  = (t & 31) * 4;
        float4 v = *(const float4*)&Cf[row*LDC3 + c4];
        *(float4*)&o0[(size_t)(m0 + pass*64 + row)*NT + n0 + c4] = v;
      }
      __syncthreads();
    }
  } else if (EPI == 4){
    // fp32, N=64: only wn==0 columns valid
    float* Cf = (float*)smem;
    if (wn == 0){
      #pragma unroll
      for (int mi = 0; mi < 4; ++mi)
        #pragma unroll
        for (int ni = 0; ni < 4; ++ni)
          #pragma unroll
          for (int r = 0; r < 4; ++r)
            Cf[(wm*64 + mi*16 + quad*4 + r)*LDCF + ni*16 + l16] = acc[mi][ni][r];
    }
    __syncthreads();
    #pragma unroll
    for (int it = 0; it < 8; ++it){
      const int row = it*16 + (t >> 4);
      const int c4  = (t & 15) * 4;
      float4 v = *(const float4*)&Cf[row*LDCF + c4];
      *(float4*)&o0[((size_t)blockIdx.z*M_ + m0 + row)*DT_ + c4] = v;
    }
  } else {
    // bf16 outputs (EPI 0 / 2) via padded LDS stage
    bf16* Cs = (bf16*)smem;
    #pragma unroll
    for (int mi = 0; mi < 4; ++mi){
      #pragma unroll
      for (int ni = 0; ni < 4; ++ni){
        const int n = n0 + wn*64 + ni*16 + l16;
        #pragma unroll
        for (int r = 0; r < 4; ++r){
          float v = acc[mi][ni][r];
          if (EPI == 0){
            if (n0 >= DI_) v = silu_f(v);          // g half
          } else { // EPI == 2
            v = softplus_f(v + bias[n]);
            v = fminf(fmaxf(v, 1e-6f), 10.f);      // delta
          }
          Cs[(wm*64 + mi*16 + quad*4 + r)*LDC + wn*64 + ni*16 + l16] = (bf16)v;
        }
      }
    }
    __syncthreads();
    #pragma unroll
    for (int it = 0; it < 8; ++it){
      const int row = it*16 + (t >> 4);
      const int c8  = (t & 15) * 8;
      bf16x8 v = *(const bf16x8*)&Cs[row*LDC + c8];
      if (EPI == 0){
        if (n0 < DI_) *(bf16x8*)&ob [(size_t)(m0+row)*DI_ + n0        + c8] = v;
        else          *(bf16x8*)&ob2[(size_t)(m0+row)*DI_ + n0 - DI_  + c8] = v;
      } else {
        *(bf16x8*)&ob[(size_t)(m0+row)*NT + n0 + c8] = v;
      }
    }
    if (EPI == 2){
      // ---- fused scan pass1: tile rows = chunks {c0, c0+1} of batch b.
      // Uses bf16-rounded delta from LDS (identical to what pass3 reads) ->
      // bit-identical to a standalone pass1.
      const int chunk = t >> 7;            // 0..1
      const int dcol  = t & 127;           // 0..127
      const int dglob = n0 + dcol;
      const float Ad  = a_of(alog, dglob);
      const int b  = m0 >> 12;             // 4096 rows per batch
      const int c0 = (m0 & 4095) >> 6;     // within-batch chunk of tile row 0
      const size_t ubase = (size_t)(m0 + chunk*64)*DI_ + dglob;
      float p = 1.f, f = 0.f;
      for (int i = 0; i < CH_; ++i){
        float dl = (float)Cs[(chunk*64 + i)*LDC + dcol];
        float ee = e_of(dl, Ad);
        float uu = (float)uq[ubase + (size_t)i*DI_];
        f = f*ee + uu;
        p *= ee;
      }
      const size_t o = ((size_t)(b*G_ + c0 + chunk))*DI_ + dglob;
      Pq[o] = p; Fq[o] = f;
    }
  }
}

// ---------------- split-K reduce: dtl = sum_z partial[z] (bf16) ----------------
__global__ __launch_bounds__(256)
void dt_reduce_kernel(const float* __restrict__ part, bf16* __restrict__ dtl){
  const int i = blockIdx.x*256 + threadIdx.x;   // m*DT + n
  float s = 0.f;
  #pragma unroll
  for (int z = 0; z < KSPL; ++z) s += part[(size_t)z*M_*DT_ + i];
  dtl[i] = (bf16)s;
}

// ---------------- depthwise causal conv (K=4) + bias + SiLU ----------------
__global__ __launch_bounds__(256)
void conv_silu_kernel(const bf16* __restrict__ xi, const float* __restrict__ cw,
                      const float* __restrict__ cb, bf16* __restrict__ ubf)
{
  const int idx = blockIdx.x*256 + threadIdx.x;    // (b,l,d) flat, coalesced in d
  const int d = idx & (DI_-1);
  const int l = (idx >> 11) & (L_-1);              // DI_=2^11, L_=2^12
  float s = cb[d];
  #pragma unroll
  for (int k = 0; k < 4; ++k){
    const int ll = l + k - 3;
    if (ll >= 0) s += (float)xi[idx + (k-3)*DI_] * cw[d*4 + k];
  }
  ubf[idx] = (bf16)silu_f(s);
}

// ---------------- scan pass3 (with inlined pass2 prefix) ----------------
__global__ __launch_bounds__(256)
void scan_pass3(const bf16* __restrict__ delta, const bf16* __restrict__ u,
                const bf16* __restrict__ g, const float* __restrict__ P,
                const float* __restrict__ F, const float* __restrict__ alog,
                const float* __restrict__ Dp, bf16* __restrict__ y)
{
  const int d = blockIdx.x*256 + threadIdx.x;
  const int c = blockIdx.y, b = blockIdx.z;
  const float Ad = a_of(alog, d);
  float s = 0.f;
  for (int cc = 0; cc < c; ++cc){
    const size_t o = ((size_t)(b*G_ + cc))*DI_ + d;
    s = F[o] + P[o]*s;
  }
  size_t base = ((size_t)(b*L_ + c*CH_))*DI_ + d;
  const float Dd = Dp[d];
  for (int i = 0; i < CH_; ++i){
    const size_t idx = base + (size_t)i*DI_;
    const float uu = (float)u[idx];
    s = s*e_of((float)delta[idx], Ad) + uu;
    float yy = s + uu*Dd;
    yy = fminf(fmaxf(yy, -1e4f), 1e4f);
    yy *= (float)g[idx];              // g = silu(z), from GEMM1 epilogue
    y[idx] = (bf16)yy;
  }
}

// ---------------- host launch ----------------
extern "C" void kernel_launch(void* const* d_in, const int* in_sizes, int n_in,
                              void* d_out, int out_size, void* d_ws, size_t ws_size,
                              hipStream_t stream)
{
  (void)in_sizes; (void)n_in; (void)out_size; (void)ws_size;
  const float* x        = (const float*)d_in[0];
  const float* in_w     = (const float*)d_in[1];
  const float* conv_w   = (const float*)d_in[2];
  const float* conv_b   = (const float*)d_in[3];
  const float* xproj_w  = (const float*)d_in[4];
  const float* dtproj_w = (const float*)d_in[5];
  const float* dtproj_b = (const float*)d_in[6];
  const float* A_log    = (const float*)d_in[7];
  const float* Dp       = (const float*)d_in[8];
  const float* out_w    = (const float*)d_in[9];

  char* base = (char*)d_ws;
  const size_t MiB = 1024*1024;
  // Region 0 [0,64 MiB): xi_bf(32) [p1] -> part(16) [dt] -> delta_bf(32) [e+scan]
  bf16*  xi_bf = (bf16*) (base + 0);
  float* part  = (float*)(base + 0);          // 8*8192*64*4 = 16 MiB
  bf16*  dl_bf = (bf16*) (base + 0);          // delta, 32 MiB
  bf16*  x_bf  = (bf16*) (base + 32*MiB);     // 16 MiB
  bf16*  w1_bf = (bf16*) (base + 48*MiB);     // 8 MiB
  bf16*  g_bf  = (bf16*) (base + 64*MiB);     // 32 MiB
  bf16*  u_bf  = (bf16*) (base + 96*MiB);     // 32 MiB
  bf16*  y_bf  = (bf16*) (base + 128*MiB);    // 32 MiB
  bf16*  wo_bf = (bf16*) (base + 160*MiB);    // 4 MiB
  bf16*  xp_bf = (bf16*) (base + 164*MiB);    // 0.25 MiB
  bf16*  dp_bf = (bf16*) (base + 165*MiB);    // 0.25 MiB
  bf16*  dtl_bf= (bf16*) (base + 166*MiB);    // 1 MiB
  float* P     = (float*)(base + 167*MiB);    // 1 MiB
  float* F     = (float*)(base + 168*MiB);    // 1 MiB  -> total 169 MiB (fits)

  const int c0 = (M_*DM_)/4, c1 = (2*DI_*DM_)/4, c2 = (DT_*DI_)/4,
            c3 = (DI_*DT_)/4, c4 = (DM_*DI_)/4;
  const int ctot = c0+c1+c2+c3+c4;
  cvt_all_kernel<<<(ctot+255)/256, 256, 0, stream>>>(
      (const float4*)x,        (bf16x4*)x_bf,  c0,
      (const float4*)in_w,     (bf16x4*)w1_bf, c1,
      (const float4*)xproj_w,  (bf16x4*)xp_bf, c2,
      (const float4*)dtproj_w, (bf16x4*)dp_bf, c3,
      (const float4*)out_w,    (bf16x4*)wo_bf, c4);

  // 1) xz = x @ in_proj_w^T ; split -> xi (bf16), g=silu(z) (bf16)
  gemm_bt<0, M_, 2*DI_, DM_><<<dim3((2*DI_)/128, M_/128), 256, 0, stream>>>(
      x_bf, w1_bf, nullptr, xi_bf, g_bf, nullptr,
      nullptr, nullptr, nullptr, nullptr);
  // 2) depthwise causal conv + bias + silu -> u (bf16)
  conv_silu_kernel<<<(M_*DI_)/256, 256, 0, stream>>>(xi_bf, conv_w, conv_b, u_bf);
  // 3) dt_low = u @ x_proj_w^T, split-K=8 -> fp32 partials (xi region now dead)
  gemm_bt<4, M_, DT_, KSL><<<dim3(1, M_/128, KSPL), 256, 0, stream>>>(
      u_bf, xp_bf, part, nullptr, nullptr, nullptr,
      nullptr, nullptr, nullptr, nullptr);
  dt_reduce_kernel<<<(M_*DT_)/256, 256, 0, stream>>>(part, dtl_bf);
  // 4) delta = clip(softplus(dtl @ dt_proj_w^T + b)) -> bf16 + fused scan pass1
  gemm_bt<2, M_, DI_, DT_><<<dim3(DI_/128, M_/128), 256, 0, stream>>>(
      dtl_bf, dp_bf, nullptr, dl_bf, nullptr, dtproj_b,
      A_log, u_bf, P, F);
  // 5) scan: prefix from P,F + within-chunk states + skip + gate -> y (bf16)
  scan_pass3<<<dim3(DI_/256, G_, B_), 256, 0, stream>>>(
      dl_bf, u_bf, g_bf, P, F, A_log, Dp, y_bf);
  // 6) out = y @ out_proj_w^T  (fp32 output)
  gemm_bt<3, M_, DM_, DI_><<<dim3(DM_/128, M_/128), 256, 0, stream>>>(
      y_bf, wo_bf, (float*)d_out, nullptr, nullptr, nullptr,
      nullptr, nullptr, nullptr, nullptr);
}